// Round 1
// baseline (249.316 us; speedup 1.0000x reference)
//
#include <hip/hip_runtime.h>

#define T_DIM 60
#define M_DIM 8

__global__ void init_kernel(float* __restrict__ ws_npred, float* __restrict__ out) {
    int i = threadIdx.x;
    if (i < T_DIM) ws_npred[i] = 0.0f;
    if (i == 0) out[0] = 0.0f;
}

// n_pred[t] = sum_n mask[n,t]; mask is (N,T) flat, coalesced grid-stride read.
__global__ void npred_kernel(const float* __restrict__ mask,
                             float* __restrict__ ws_npred, int NT) {
    __shared__ float bins[T_DIM];
    for (int j = threadIdx.x; j < T_DIM; j += blockDim.x) bins[j] = 0.0f;
    __syncthreads();
    int stride = gridDim.x * blockDim.x;
    for (int i = blockIdx.x * blockDim.x + threadIdx.x; i < NT; i += stride) {
        int t = i % T_DIM;
        atomicAdd(&bins[t], mask[i]);
    }
    __syncthreads();
    for (int j = threadIdx.x; j < T_DIM; j += blockDim.x)
        atomicAdd(&ws_npred[j], bins[j]);
}

// One thread per (n,t). Closed-form 2x2 "Cholesky": det = ac - b^2,
// maha = (c d1^2 - 2b d1 d2 + a d2^2)/det, log|L| = 0.5 log det.
__global__ __launch_bounds__(256)
void loss_kernel(const float* __restrict__ mu,
                 const float* __restrict__ sigma,
                 const float* __restrict__ pi,
                 const float* __restrict__ x,
                 const float* __restrict__ mask,
                 const float* __restrict__ ws_npred,
                 float* __restrict__ out, int NT) {
    const float LOG_2PI = 1.8378770664093453f;
    int i = blockIdx.x * blockDim.x + threadIdx.x;
    float contrib = 0.0f;
    if (i < NT) {
        int n = i / T_DIM;
        int t = i - n * T_DIM;

        float2 xv = ((const float2*)x)[i];
        float mk = mask[i];

        // mu: 16 consecutive floats at i*16 (64B-aligned) -> 4x float4
        const float4* mu4 = (const float4*)(mu + (size_t)i * 16);
        float4 mv0 = mu4[0], mv1 = mu4[1], mv2 = mu4[2], mv3 = mu4[3];
        // sigma: 32 consecutive floats at i*32 (128B-aligned) -> 8x float4
        const float4* sg4 = (const float4*)(sigma + (size_t)i * 32);
        float4 sg[M_DIM];
#pragma unroll
        for (int m = 0; m < M_DIM; ++m) sg[m] = sg4[m];
        // pi: 8 floats at n*8 (32B-aligned); reused by 60 threads -> L1/L2 hit
        const float4* pi4 = (const float4*)(pi + (size_t)n * 8);
        float4 p0 = pi4[0], p1 = pi4[1];

        float mus[2 * M_DIM] = {mv0.x, mv0.y, mv0.z, mv0.w,
                                mv1.x, mv1.y, mv1.z, mv1.w,
                                mv2.x, mv2.y, mv2.z, mv2.w,
                                mv3.x, mv3.y, mv3.z, mv3.w};
        float pis[M_DIM] = {p0.x, p0.y, p0.z, p0.w, p1.x, p1.y, p1.z, p1.w};

        float lp[M_DIM];
#pragma unroll
        for (int m = 0; m < M_DIM; ++m) {
            float a = sg[m].x, b = sg[m].y, c = sg[m].w;
            float d1 = xv.x - mus[2 * m];
            float d2 = xv.y - mus[2 * m + 1];
            float det = a * c - b * b;        // SPD: det > 0 (>= 0.25 here)
            float maha = (c * d1 * d1 - 2.0f * b * d1 * d2 + a * d2 * d2) / det;
            float mvn = -LOG_2PI - 0.5f * (maha + __logf(det));
            lp[m] = pis[m] + mvn;
        }

        // gmm_lp = lse_m(pi + mvn) - lse_m(pi)
        float mx = lp[0];
#pragma unroll
        for (int m = 1; m < M_DIM; ++m) mx = fmaxf(mx, lp[m]);
        float s = 0.0f;
#pragma unroll
        for (int m = 0; m < M_DIM; ++m) s += __expf(lp[m] - mx);
        float lse_num = mx + __logf(s);

        float pmx = pis[0];
#pragma unroll
        for (int m = 1; m < M_DIM; ++m) pmx = fmaxf(pmx, pis[m]);
        float ps = 0.0f;
#pragma unroll
        for (int m = 0; m < M_DIM; ++m) ps += __expf(pis[m] - pmx);
        float lse_pi = pmx + __logf(ps);

        float loss = lse_pi - lse_num;        // -gmm_lp
        contrib = loss * mk / ws_npred[t];
    }

    // wave (64) shuffle reduce -> LDS -> one atomic per block
#pragma unroll
    for (int off = 32; off > 0; off >>= 1)
        contrib += __shfl_down(contrib, off);
    __shared__ float wsum[4];
    int lane = threadIdx.x & 63;
    int wid = threadIdx.x >> 6;
    if (lane == 0) wsum[wid] = contrib;
    __syncthreads();
    if (threadIdx.x == 0) {
        float v = wsum[0] + wsum[1] + wsum[2] + wsum[3];
        atomicAdd(out, v);
    }
}

extern "C" void kernel_launch(void* const* d_in, const int* in_sizes, int n_in,
                              void* d_out, int out_size, void* d_ws, size_t ws_size,
                              hipStream_t stream) {
    const float* mu    = (const float*)d_in[0];   // (N,T,M,K)
    const float* sigma = (const float*)d_in[1];   // (N,T,M,K,K)
    const float* pi    = (const float*)d_in[2];   // (N,M)
    const float* x     = (const float*)d_in[3];   // (N,T,K)
    const float* mask  = (const float*)d_in[4];   // (N,T)
    float* out = (float*)d_out;
    float* ws_npred = (float*)d_ws;               // 60 floats

    int NT = in_sizes[4];                          // N*T = 983040

    hipLaunchKernelGGL(init_kernel, dim3(1), dim3(64), 0, stream, ws_npred, out);
    hipLaunchKernelGGL(npred_kernel, dim3(240), dim3(256), 0, stream,
                       mask, ws_npred, NT);
    hipLaunchKernelGGL(loss_kernel, dim3((NT + 255) / 256), dim3(256), 0, stream,
                       mu, sigma, pi, x, mask, ws_npred, out, NT);
}